// Round 11
// baseline (229.130 us; speedup 1.0000x reference)
//
#include <hip/hip_runtime.h>
#include <stdint.h>

#define BATCH 2048
#define NCHUNK 65536
#define EMBED 512
#define CAND_CAP 256
#define RESCORE 32
#define QSCALE 32.0f   // i8 quant scale; clip at 127/32 = 3.97 sigma

typedef __attribute__((ext_vector_type(4))) int i32x4;

__device__ __forceinline__ unsigned q8(float x) {
    float c = fminf(fmaxf(x * QSCALE, -127.0f), 127.0f);
    int v = (int)rintf(c);
    return (unsigned)(v & 0xff);
}

// ---------------- K1: convert Q,I to i8 + fused tau & cnt-zero ----------------
__global__ __launch_bounds__(256) void k_convert(
    const float* __restrict__ Q, const float* __restrict__ I,
    unsigned char* __restrict__ Qi, unsigned char* __restrict__ Ii,
    float* __restrict__ tau, int* __restrict__ cnt) {
    long long i = (long long)blockIdx.x * 256 + threadIdx.x;   // one thread = 8 elems
    const long long NI8 = (long long)NCHUNK * EMBED / 8;       // 4194304 (block-aligned)
    if (i < NI8) {
        const float* src = I + i * 8;
        float4 a = *(const float4*)src;
        float4 b = *(const float4*)(src + 4);
        uint2 o;
        o.x = q8(a.x) | (q8(a.y) << 8) | (q8(a.z) << 16) | (q8(a.w) << 24);
        o.y = q8(b.x) | (q8(b.y) << 8) | (q8(b.z) << 16) | (q8(b.w) << 24);
        *(uint2*)(Ii + i * 8) = o;
    } else {
        long long j = i - NI8;                 // Q 8-elem group index
        const float* src = Q + j * 8;
        float4 a = *(const float4*)src;
        float4 b = *(const float4*)(src + 4);
        uint2 o;
        o.x = q8(a.x) | (q8(a.y) << 8) | (q8(a.z) << 16) | (q8(a.w) << 24);
        o.y = q8(b.x) | (q8(b.y) << 8) | (q8(b.z) << 16) | (q8(b.w) << 24);
        *(uint2*)(Qi + j * 8) = o;
        float s = a.x * a.x + a.y * a.y + a.z * a.z + a.w * a.w
                + b.x * b.x + b.y * b.y + b.z * b.z + b.w * b.w;
        for (int off = 32; off; off >>= 1) s += __shfl_xor(s, off);
        if ((threadIdx.x & 63) == 0) {
            int row = (int)(j >> 6);           // 64 groups per 512-elem row
            tau[row] = 3.0f * sqrtf(s);
            cnt[row] = 0;
        }
    }
}

// ---------------- K2: round-6 kernel, LDS trimmed to exactly 32 KB ----------------
// Only change vs the 110us round-6/10 kernel: tauL removed from LDS (tau read
// from global in the epilogue, L2-hot) -> LDS_Block_Size 33280 -> 32768,
// clearing the 32KB boundary for +1 resident block/CU.
#define BM 128
#define BN 128
#define BKB 128   // K-bytes (i8 elems) per step

__device__ __forceinline__ void g2l16(const void* g, void* l) {
    __builtin_amdgcn_global_load_lds(
        (const __attribute__((address_space(1))) unsigned int*)g,
        (__attribute__((address_space(3))) unsigned int*)l, 16, 0, 0);
}

__global__ __launch_bounds__(256, 4) void k_gemm(
    const unsigned char* __restrict__ Qi, const unsigned char* __restrict__ Ii,
    const float* __restrict__ tau,
    float* __restrict__ cand_s, int* __restrict__ cand_i, int* __restrict__ cnt) {
    __shared__ __align__(16) unsigned char As[BM * BKB];   // 16 KB, chunk-swizzled
    __shared__ __align__(16) unsigned char Bs[BN * BKB];   // 16 KB, chunk-swizzled

    // XCD-chunked swizzle: each XCD owns 64 contiguous n-tiles; 16 m-tiles
    // consecutive per n-tile -> B-panel L2 reuse inside one XCD.
    int id = blockIdx.x;
    int xcd = id & 7, r = id >> 3;
    int mt = r & 15;
    int nt = (xcd << 6) | (r >> 4);
    int m0 = mt * BM, n0 = nt * BN;

    int tid = threadIdx.x, lane = tid & 63, w = tid >> 6;
    int wm = (w >> 1) * 64, wn = (w & 1) * 64;
    int l15 = lane & 15, hi = lane >> 4;

    i32x4 acc[4][4];
#pragma unroll
    for (int mi = 0; mi < 4; ++mi)
#pragma unroll
        for (int ni = 0; ni < 4; ++ni) acc[mi][ni] = (i32x4){0, 0, 0, 0};

    for (int ks = 0; ks < EMBED; ks += BKB) {
        __syncthreads();   // previous iter's LDS reads done
#pragma unroll
        for (int i = 0; i < 4; ++i) {
            int t2 = i * 256 + tid;            // 0..1023, 16B chunks, lane-linear dest
            int row = t2 >> 3, j = t2 & 7;     // 8 chunks per 128B row
            int src = j ^ (row & 7);           // inverse source swizzle (rule #21)
            g2l16(Qi + (m0 + row) * EMBED + ks + (src << 4), As + t2 * 16);
            g2l16(Ii + (n0 + row) * EMBED + ks + (src << 4), Bs + t2 * 16);
        }
        __syncthreads();   // compiler drains vmcnt before barrier
#pragma unroll
        for (int kk = 0; kk < 2; ++kk) {       // two K=64 MFMA sub-steps
            i32x4 af[4], bfr[4];
#pragma unroll
            for (int mi = 0; mi < 4; ++mi) {
                int row = wm + mi * 16 + l15;
                int j = ((kk << 2) | hi) ^ (row & 7);
                af[mi] = *(const i32x4*)(As + row * BKB + (j << 4));
            }
#pragma unroll
            for (int ni = 0; ni < 4; ++ni) {
                int row = wn + ni * 16 + l15;
                int j = ((kk << 2) | hi) ^ (row & 7);
                bfr[ni] = *(const i32x4*)(Bs + row * BKB + (j << 4));
            }
#pragma unroll
            for (int mi = 0; mi < 4; ++mi)
#pragma unroll
                for (int ni = 0; ni < 4; ++ni)
                    acc[mi][ni] = __builtin_amdgcn_mfma_i32_16x16x64_i8(
                        af[mi], bfr[ni], acc[mi][ni], 0, 0, 0);
        }
    }

    // Epilogue: C/D layout col=lane&15, row=(lane>>4)*4+reg (dtype-independent).
    // score = acc / (32*32). tau read from global (L2-hot, epilogue-only).
    const float inv_s2 = 1.0f / (QSCALE * QSCALE);
#pragma unroll
    for (int mi = 0; mi < 4; ++mi)
#pragma unroll
        for (int rr = 0; rr < 4; ++rr) {
            int ml = wm + mi * 16 + hi * 4 + rr;
            int m = m0 + ml;
            float t = tau[m];
#pragma unroll
            for (int ni = 0; ni < 4; ++ni) {
                float s = (float)acc[mi][ni][rr] * inv_s2;
                if (s > t) {
                    int chunk = n0 + wn + ni * 16 + l15;
                    int slot = atomicAdd(&cnt[m], 1);
                    if (slot < CAND_CAP) {
                        cand_s[m * CAND_CAP + slot] = s;
                        cand_i[m * CAND_CAP + slot] = chunk;
                    }
                }
            }
        }
}

// ---------------- K3: per-query finalize, chunked staging (22 KB LDS) ----------------
// Exact sequential f32 FMA chain per candidate (k ascending, single acc) —
// bit-identical arithmetic to the previously-passing version, now processed
// in 4 chunks of 128 k-elems: vbuf 32 rows x 132-word stride (16B aligned)
// = 16.9 KB; total LDS ~22 KB -> 7 blocks/CU (was 4) for ~1.75x outstanding
// gather requests on the 128 MB candidate-row gather (the measured limiter).
#define VSTW 132
__global__ __launch_bounds__(64) void k_final(
    const float* __restrict__ Q, const float* __restrict__ I,
    const int* __restrict__ posn, const int* __restrict__ topk,
    const float* __restrict__ cand_s, const int* __restrict__ cand_i,
    const int* __restrict__ cnt, float* __restrict__ out) {
    __shared__ float ls[CAND_CAP];
    __shared__ int   li[CAND_CAP];
    __shared__ int   selc[RESCORE];
    __shared__ float fsc[RESCORE];
    __shared__ float qrow[EMBED];
    __shared__ float vbuf[RESCORE * VSTW];   // 32*132*4 = 16896 B

    int q = blockIdx.x, lane = threadIdx.x;
    int c = cnt[q]; if (c > CAND_CAP) c = CAND_CAP;

    const float* qp = Q + q * EMBED + lane * 8;
    *(float4*)&qrow[lane * 8]     = *(const float4*)qp;
    *(float4*)&qrow[lane * 8 + 4] = *(const float4*)(qp + 4);

    for (int i = lane; i < CAND_CAP; i += 64) {
        ls[i] = (i < c) ? cand_s[q * CAND_CAP + i] : -3.0e38f;
        li[i] = (i < c) ? cand_i[q * CAND_CAP + i] : 0;
    }
    if (lane < RESCORE) selc[lane] = 0;
    __syncthreads();

    int nsel = c < RESCORE ? c : RESCORE;
    // approx top-nsel by i8 GEMM score (error 0.31 << rank16->32 gap -> superset)
    for (int s = 0; s < nsel; ++s) {
        float best = -3.0e38f; int bs = 0;
#pragma unroll
        for (int rr = 0; rr < 4; ++rr) {
            int sl = rr * 64 + lane;
            float v = ls[sl];
            if (v > best) { best = v; bs = sl; }
        }
        for (int o = 32; o; o >>= 1) {
            float b2 = __shfl_xor(best, o); int s2 = __shfl_xor(bs, o);
            if (b2 > best || (b2 == best && s2 < bs)) { best = b2; bs = s2; }
        }
        if (lane == 0) { selc[s] = li[bs]; ls[bs] = -3.0e38f; }
        __syncthreads();
    }

    // exact f32 sequential-FMA rescore, 4 chunks of 128 k-elems, 32 parallel chains
    float acc = 0.0f;
    for (int ch = 0; ch < 4; ++ch) {
        __syncthreads();   // previous chunk's chain reads done
#pragma unroll
        for (int i = 0; i < 16; ++i) {
            int idx = i * 64 + lane;           // 0..1023 float4 slots
            int row = idx >> 5, cc = idx & 31; // 32 float4 per row
            int chunk = selc[row];             // row>=nsel -> 0 (harmless)
            float4 v = *(const float4*)(I + (long long)chunk * EMBED + ch * 128 + cc * 4);
            *(float4*)&vbuf[row * VSTW + cc * 4] = v;
        }
        __syncthreads();
        if (lane < RESCORE) {
            const float* vr = &vbuf[lane * VSTW];
            const float* qr = &qrow[ch * 128];
#pragma unroll
            for (int k4 = 0; k4 < 32; ++k4) {
                float4 v  = *(const float4*)&vr[k4 * 4];
                float4 qq = *(const float4*)&qr[k4 * 4];
                acc = fmaf(qq.x, v.x, acc);    // strict k-ascending order, f32
                acc = fmaf(qq.y, v.y, acc);
                acc = fmaf(qq.z, v.z, acc);
                acc = fmaf(qq.w, v.w, acc);
            }
        }
    }
    if (lane < RESCORE) fsc[lane] = (lane < nsel) ? acc : -3.0e38f;
    __syncthreads();

    // final top-k by (f32 score desc, chunk asc) — matches stable top_k
    int tk = topk[0]; if (tk > 16) tk = 16; if (tk < 0) tk = 0;
    float myv = (lane < RESCORE) ? fsc[lane] : -3.0e38f;
    int myc = (lane < RESCORE) ? selc[lane] : 0x7fffffff;
    int mysl = lane;
    for (int j = 0; j < 16; ++j) {
        if (j < tk) {
            float v = myv; int gc = myc; int sl = mysl;
            for (int o = 32; o; o >>= 1) {
                float v2 = __shfl_xor(v, o); int c2 = __shfl_xor(gc, o); int s2 = __shfl_xor(sl, o);
                if (v2 > v || (v2 == v && c2 < gc)) { v = v2; gc = c2; sl = s2; }
            }
            if (lane == 0) {
                out[q * 16 + j] = v;
                out[BATCH * 16 + q * 16 + j] = (float)posn[gc];
            }
            if (mysl == sl) myv = -3.0e38f;
        } else if (lane == 0) {
            out[q * 16 + j] = 0.0f;
            out[BATCH * 16 + q * 16 + j] = 0.0f;
        }
    }
}

// ---------------- launcher ----------------
extern "C" void kernel_launch(void* const* d_in, const int* in_sizes, int n_in,
                              void* d_out, int out_size, void* d_ws, size_t ws_size,
                              hipStream_t stream) {
    const float* Q    = (const float*)d_in[0];
    const float* I    = (const float*)d_in[1];
    const int*   posn = (const int*)d_in[2];
    const int*   topk = (const int*)d_in[3];
    float* out = (float*)d_out;

    char* ws = (char*)d_ws;
    unsigned char* Ii = (unsigned char*)ws;                       // 33,554,432 B
    unsigned char* Qi = (unsigned char*)(ws + 33554432);          //  1,048,576 B
    float* tau    = (float*)(ws + 34603008);                      //      8,192 B
    int*   cnt    = (int*)(ws + 34611200);                        //      8,192 B
    float* cand_s = (float*)(ws + 34619392);                      //  2,097,152 B
    int*   cand_i = (int*)(ws + 36716544);                        //  2,097,152 B -> 38.8MB total

    k_convert<<<16896, 256, 0, stream>>>(Q, I, Qi, Ii, tau, cnt);
    k_gemm<<<8192, 256, 0, stream>>>(Qi, Ii, tau, cand_s, cand_i, cnt);
    k_final<<<BATCH, 64, 0, stream>>>(Q, I, posn, topk, cand_s, cand_i, cnt, out);
}

// Round 12
// 207.163 us; speedup vs baseline: 1.1060x; 1.1060x over previous
//
#include <hip/hip_runtime.h>
#include <stdint.h>

#define BATCH 2048
#define NCHUNK 65536
#define EMBED 512
#define CAND_CAP 256
#define RESCORE 32
#define QSCALE 32.0f   // i8 quant scale; clip at 127/32 = 3.97 sigma

typedef __attribute__((ext_vector_type(4))) int i32x4;

__device__ __forceinline__ unsigned q8(float x) {
    float c = fminf(fmaxf(x * QSCALE, -127.0f), 127.0f);
    int v = (int)rintf(c);
    return (unsigned)(v & 0xff);
}

// ---------------- K1: convert Q,I to i8 + fused tau & cnt-zero ----------------
__global__ __launch_bounds__(256) void k_convert(
    const float* __restrict__ Q, const float* __restrict__ I,
    unsigned char* __restrict__ Qi, unsigned char* __restrict__ Ii,
    float* __restrict__ tau, int* __restrict__ cnt) {
    long long i = (long long)blockIdx.x * 256 + threadIdx.x;   // one thread = 8 elems
    const long long NI8 = (long long)NCHUNK * EMBED / 8;       // 4194304 (block-aligned)
    if (i < NI8) {
        const float* src = I + i * 8;
        float4 a = *(const float4*)src;
        float4 b = *(const float4*)(src + 4);
        uint2 o;
        o.x = q8(a.x) | (q8(a.y) << 8) | (q8(a.z) << 16) | (q8(a.w) << 24);
        o.y = q8(b.x) | (q8(b.y) << 8) | (q8(b.z) << 16) | (q8(b.w) << 24);
        *(uint2*)(Ii + i * 8) = o;
    } else {
        long long j = i - NI8;                 // Q 8-elem group index
        const float* src = Q + j * 8;
        float4 a = *(const float4*)src;
        float4 b = *(const float4*)(src + 4);
        uint2 o;
        o.x = q8(a.x) | (q8(a.y) << 8) | (q8(a.z) << 16) | (q8(a.w) << 24);
        o.y = q8(b.x) | (q8(b.y) << 8) | (q8(b.z) << 16) | (q8(b.w) << 24);
        *(uint2*)(Qi + j * 8) = o;
        float s = a.x * a.x + a.y * a.y + a.z * a.z + a.w * a.w
                + b.x * b.x + b.y * b.y + b.z * b.z + b.w * b.w;
        for (int off = 32; off; off >>= 1) s += __shfl_xor(s, off);
        if ((threadIdx.x & 63) == 0) {
            int row = (int)(j >> 6);           // 64 groups per 512-elem row
            tau[row] = 3.0f * sqrtf(s);
            cnt[row] = 0;
        }
    }
}

// ---------------- K2: round-10 kernel, EXACT (known 108-110us) ----------------
#define BM 128
#define BN 128
#define BKB 128   // K-bytes (i8 elems) per step

__device__ __forceinline__ void g2l16(const void* g, void* l) {
    __builtin_amdgcn_global_load_lds(
        (const __attribute__((address_space(1))) unsigned int*)g,
        (__attribute__((address_space(3))) unsigned int*)l, 16, 0, 0);
}

__global__ __launch_bounds__(256, 4) void k_gemm(
    const unsigned char* __restrict__ Qi, const unsigned char* __restrict__ Ii,
    const float* __restrict__ tau,
    float* __restrict__ cand_s, int* __restrict__ cand_i, int* __restrict__ cnt) {
    __shared__ __align__(16) unsigned char As[BM * BKB];   // 16 KB, chunk-swizzled
    __shared__ __align__(16) unsigned char Bs[BN * BKB];   // 16 KB, chunk-swizzled
    __shared__ float tauL[BM];

    // XCD-chunked swizzle: each XCD owns 64 contiguous n-tiles; 16 m-tiles
    // consecutive per n-tile -> B-panel L2 reuse inside one XCD.
    int id = blockIdx.x;
    int xcd = id & 7, r = id >> 3;
    int mt = r & 15;
    int nt = (xcd << 6) | (r >> 4);
    int m0 = mt * BM, n0 = nt * BN;

    int tid = threadIdx.x, lane = tid & 63, w = tid >> 6;
    int wm = (w >> 1) * 64, wn = (w & 1) * 64;
    int l15 = lane & 15, hi = lane >> 4;

    if (tid < BM) tauL[tid] = tau[m0 + tid];

    i32x4 acc[4][4];
#pragma unroll
    for (int mi = 0; mi < 4; ++mi)
#pragma unroll
        for (int ni = 0; ni < 4; ++ni) acc[mi][ni] = (i32x4){0, 0, 0, 0};

    for (int ks = 0; ks < EMBED; ks += BKB) {
        __syncthreads();   // previous iter's LDS reads done (also covers tauL)
#pragma unroll
        for (int i = 0; i < 4; ++i) {
            int t2 = i * 256 + tid;            // 0..1023, 16B chunks, lane-linear dest
            int row = t2 >> 3, j = t2 & 7;     // 8 chunks per 128B row
            int src = j ^ (row & 7);           // inverse source swizzle (rule #21)
            g2l16(Qi + (m0 + row) * EMBED + ks + (src << 4), As + t2 * 16);
            g2l16(Ii + (n0 + row) * EMBED + ks + (src << 4), Bs + t2 * 16);
        }
        __syncthreads();   // compiler drains vmcnt before barrier
#pragma unroll
        for (int kk = 0; kk < 2; ++kk) {       // two K=64 MFMA sub-steps
            i32x4 af[4], bfr[4];
#pragma unroll
            for (int mi = 0; mi < 4; ++mi) {
                int row = wm + mi * 16 + l15;
                int j = ((kk << 2) | hi) ^ (row & 7);
                af[mi] = *(const i32x4*)(As + row * BKB + (j << 4));
            }
#pragma unroll
            for (int ni = 0; ni < 4; ++ni) {
                int row = wn + ni * 16 + l15;
                int j = ((kk << 2) | hi) ^ (row & 7);
                bfr[ni] = *(const i32x4*)(Bs + row * BKB + (j << 4));
            }
#pragma unroll
            for (int mi = 0; mi < 4; ++mi)
#pragma unroll
                for (int ni = 0; ni < 4; ++ni)
                    acc[mi][ni] = __builtin_amdgcn_mfma_i32_16x16x64_i8(
                        af[mi], bfr[ni], acc[mi][ni], 0, 0, 0);
        }
    }

    // Epilogue: C/D layout col=lane&15, row=(lane>>4)*4+reg (dtype-independent).
    // score = acc / (32*32). Threshold filter -> rare atomics.
    const float inv_s2 = 1.0f / (QSCALE * QSCALE);
#pragma unroll
    for (int mi = 0; mi < 4; ++mi)
#pragma unroll
        for (int rr = 0; rr < 4; ++rr) {
            int ml = wm + mi * 16 + hi * 4 + rr;
            float t = tauL[ml];
            int m = m0 + ml;
#pragma unroll
            for (int ni = 0; ni < 4; ++ni) {
                float s = (float)acc[mi][ni][rr] * inv_s2;
                if (s > t) {
                    int chunk = n0 + wn + ni * 16 + l15;
                    int slot = atomicAdd(&cnt[m], 1);
                    if (slot < CAND_CAP) {
                        cand_s[m * CAND_CAP + slot] = s;
                        cand_i[m * CAND_CAP + slot] = chunk;
                    }
                }
            }
        }
}

// ---------------- K3: per-query finalize, 128 threads (2-wave gather) ----------------
// The gather (32 rows x 2KB/query, 134MB total) is latency-bound; 128 threads
// double the in-flight float4 loads per block while LDS stays ~21KB (7
// blocks/CU). Selection + exact sequential-f32-FMA chains stay on wave 0
// (bit-identical arithmetic to the passing round-10/11 versions); wave 1
// executes matching __syncthreads counts and idles through serial phases.
#define VSTW 132
__global__ __launch_bounds__(128) void k_final(
    const float* __restrict__ Q, const float* __restrict__ I,
    const int* __restrict__ posn, const int* __restrict__ topk,
    const float* __restrict__ cand_s, const int* __restrict__ cand_i,
    const int* __restrict__ cnt, float* __restrict__ out) {
    __shared__ float ls[CAND_CAP];
    __shared__ int   li[CAND_CAP];
    __shared__ int   selc[RESCORE];
    __shared__ float fsc[RESCORE];
    __shared__ float qrow[EMBED];
    __shared__ float vbuf[RESCORE * VSTW];   // 32*132*4 = 16896 B

    int q = blockIdx.x, tid = threadIdx.x, lane = tid & 63;
    int c = cnt[q]; if (c > CAND_CAP) c = CAND_CAP;

    // stage q: 128 threads x 1 float4
    *(float4*)&qrow[tid * 4] = *(const float4*)(Q + q * EMBED + tid * 4);

    for (int i = tid; i < CAND_CAP; i += 128) {
        ls[i] = (i < c) ? cand_s[q * CAND_CAP + i] : -3.0e38f;
        li[i] = (i < c) ? cand_i[q * CAND_CAP + i] : 0;
    }
    if (tid < RESCORE) selc[tid] = 0;
    __syncthreads();

    int nsel = c < RESCORE ? c : RESCORE;
    // approx top-nsel by i8 GEMM score — wave 0 only (error << rank16->32 gap)
    for (int s = 0; s < nsel; ++s) {
        if (tid < 64) {
            float best = -3.0e38f; int bs = 0;
#pragma unroll
            for (int rr = 0; rr < 4; ++rr) {
                int sl = rr * 64 + lane;
                float v = ls[sl];
                if (v > best) { best = v; bs = sl; }
            }
            for (int o = 32; o; o >>= 1) {
                float b2 = __shfl_xor(best, o); int s2 = __shfl_xor(bs, o);
                if (b2 > best || (b2 == best && s2 < bs)) { best = b2; bs = s2; }
            }
            if (lane == 0) { selc[s] = li[bs]; ls[bs] = -3.0e38f; }
        }
        __syncthreads();
    }

    // exact f32 sequential-FMA rescore, 4 chunks of 128 k-elems;
    // gather staged by ALL 128 threads, chains on lanes 0-31 of wave 0
    float acc = 0.0f;
    for (int ch = 0; ch < 4; ++ch) {
        __syncthreads();   // previous chunk's chain reads done
#pragma unroll
        for (int i = 0; i < 8; ++i) {
            int idx = i * 128 + tid;           // 0..1023 float4 slots
            int row = idx >> 5, cc = idx & 31; // 32 float4 per row
            int chunk = selc[row];             // row>=nsel -> 0 (harmless)
            float4 v = *(const float4*)(I + (long long)chunk * EMBED + ch * 128 + cc * 4);
            *(float4*)&vbuf[row * VSTW + cc * 4] = v;
        }
        __syncthreads();
        if (tid < RESCORE) {
            const float* vr = &vbuf[tid * VSTW];
            const float* qr = &qrow[ch * 128];
#pragma unroll
            for (int k4 = 0; k4 < 32; ++k4) {
                float4 v  = *(const float4*)&vr[k4 * 4];
                float4 qq = *(const float4*)&qr[k4 * 4];
                acc = fmaf(qq.x, v.x, acc);    // strict k-ascending order, f32
                acc = fmaf(qq.y, v.y, acc);
                acc = fmaf(qq.z, v.z, acc);
                acc = fmaf(qq.w, v.w, acc);
            }
        }
    }
    if (tid < RESCORE) fsc[tid] = (tid < nsel) ? acc : -3.0e38f;
    __syncthreads();

    // final top-k by (f32 score desc, chunk asc) — wave 0 only; matches stable top_k
    if (tid < 64) {
        int tk = topk[0]; if (tk > 16) tk = 16; if (tk < 0) tk = 0;
        float myv = (lane < RESCORE) ? fsc[lane] : -3.0e38f;
        int myc = (lane < RESCORE) ? selc[lane] : 0x7fffffff;
        int mysl = lane;
        for (int j = 0; j < 16; ++j) {
            if (j < tk) {
                float v = myv; int gc = myc; int sl = mysl;
                for (int o = 32; o; o >>= 1) {
                    float v2 = __shfl_xor(v, o); int c2 = __shfl_xor(gc, o); int s2 = __shfl_xor(sl, o);
                    if (v2 > v || (v2 == v && c2 < gc)) { v = v2; gc = c2; sl = s2; }
                }
                if (lane == 0) {
                    out[q * 16 + j] = v;
                    out[BATCH * 16 + q * 16 + j] = (float)posn[gc];
                }
                if (mysl == sl) myv = -3.0e38f;
            } else if (lane == 0) {
                out[q * 16 + j] = 0.0f;
                out[BATCH * 16 + q * 16 + j] = 0.0f;
            }
        }
    }
}

// ---------------- launcher ----------------
extern "C" void kernel_launch(void* const* d_in, const int* in_sizes, int n_in,
                              void* d_out, int out_size, void* d_ws, size_t ws_size,
                              hipStream_t stream) {
    const float* Q    = (const float*)d_in[0];
    const float* I    = (const float*)d_in[1];
    const int*   posn = (const int*)d_in[2];
    const int*   topk = (const int*)d_in[3];
    float* out = (float*)d_out;

    char* ws = (char*)d_ws;
    unsigned char* Ii = (unsigned char*)ws;                       // 33,554,432 B
    unsigned char* Qi = (unsigned char*)(ws + 33554432);          //  1,048,576 B
    float* tau    = (float*)(ws + 34603008);                      //      8,192 B
    int*   cnt    = (int*)(ws + 34611200);                        //      8,192 B
    float* cand_s = (float*)(ws + 34619392);                      //  2,097,152 B
    int*   cand_i = (int*)(ws + 36716544);                        //  2,097,152 B -> 38.8MB total

    k_convert<<<16896, 256, 0, stream>>>(Q, I, Qi, Ii, tau, cnt);
    k_gemm<<<8192, 256, 0, stream>>>(Qi, Ii, tau, cand_s, cand_i, cnt);
    k_final<<<BATCH, 128, 0, stream>>>(Q, I, posn, topk, cand_s, cand_i, cnt, out);
}